// Round 3
// baseline (512.219 us; speedup 1.0000x reference)
//
#include <hip/hip_runtime.h>
#include <stdint.h>

#define B_ROWS 8192
#define IN_DIM 4096
#define OUT_DIM 4096
#define BN_EPS 1e-5f

#define BM 256                      // batch rows per block
#define BLKN 256                    // out cols per block
#define BKB 128                     // i8 K-bytes per K-tile
#define NKT (IN_DIM / BKB)          // 32 K-tiles
#define NIT (NKT / 2)               // 16 iterations (2 K-tiles each)

typedef __attribute__((ext_vector_type(4))) int i32x4;

// ---------------------------------------------------------------------------
// fp32 -> int8 sign pack: {-1, 0, +1}. Exact. x and w fused in one launch.
// ---------------------------------------------------------------------------
__device__ __forceinline__ int sign_byte(float f) {
    int s = (f > 0.f) ? 1 : ((f < 0.f) ? -1 : 0);
    return s & 0xFF;
}

#define XN (B_ROWS * IN_DIM / 4)    // float4 count of x

__global__ void pack_both(const float* __restrict__ x, const float* __restrict__ w,
                          int* __restrict__ xb, int* __restrict__ wb) {
    int gid = blockIdx.x * blockDim.x + threadIdx.x;
    const float* src = (gid < XN) ? x : w;
    int*         dst = (gid < XN) ? xb : wb;
    int          idx = (gid < XN) ? gid : gid - XN;
    float4 v = reinterpret_cast<const float4*>(src)[idx];
    dst[idx] = sign_byte(v.x) | (sign_byte(v.y) << 8) |
               (sign_byte(v.z) << 16) | (sign_byte(v.w) << 24);
}

// ---------------------------------------------------------------------------
// 256x256 8-phase i8 MFMA GEMM, software-pipelined ds_reads.
//
// Reads for phase N+1 issue in phase N's pre-barrier window into registers
// not consumed by phase N's MFMA -> compiler emits counted lgkmcnt (no
// drain-0); LDS latency hides under the previous MFMA cluster.
//
// Per-iteration schedule (2 K-tiles; b0 = even tile, b1 = odd):
//   win  reads(next ph)      stage            MFMA          end-wait
//   p1   bb23(b0)   [4]      b1.AQ1(tc1)      alo*bb01 b0
//   p2   ahi (b0)   [8]      b1.BN1(tc1)      alo*bb23 b0
//   p3   --                  b0'.AQ0(tn0)     ahi*bb01 b0   vmcnt(6)
//   p4   alo+bb01(b1)[12]    b0'.BN0(tn0)     ahi*bb23 b0   vmcnt(4)
//   p5   bb23(b1)   [4]      b0'.AQ1(tn0)     alo*bb01 b1
//   p6   ahi (b1)   [8]      b0'.BN1(tn0)     alo*bb23 b1
//   p7   --                  b1'.AQ0(tn1)     ahi*bb01 b1   vmcnt(6)
//   p8   alo+bb01(b0')[12]   b1'.BN0(tn1)     ahi*bb23 b1   vmcnt(4)
//
// vmcnt ladder (2 loads/stage, re-audited R2->R3): p3-end drains prev
// p7/p8 (b1.AQ0,BN0) needed by p4's reads; p4-end drains p1/p2 (b1.AQ1,BN1)
// needed by p5/p6; p7-end drains p3/p4 (b0'.AQ0,BN0) needed by p8; p8-end
// drains p5/p6 (b0'.AQ1,BN1) needed by next p1/p2. Every read is issued
// after the barrier that follows the covering vmcnt (cross-wave safe).
//
// R3 FIX: prologue frag reads moved AFTER the prologue barrier — vmcnt only
// covers this wave's staging; other waves' rows need barrier separation.
// sched_barrier(0) after every s_barrier pins window reads below it.
// ---------------------------------------------------------------------------
__device__ __forceinline__ void stage_pair(const int8_t* g0, int8_t* l0) {
    __builtin_amdgcn_global_load_lds(
        (const __attribute__((address_space(1))) void*)g0,
        (__attribute__((address_space(3))) void*)l0, 16, 0, 0);
    __builtin_amdgcn_global_load_lds(
        (const __attribute__((address_space(1))) void*)(g0 + (size_t)128 * IN_DIM),
        (__attribute__((address_space(3))) void*)(l0 + 128 * BKB), 16, 0, 0);
}

template <int FB>
__device__ __forceinline__ void load_frag4(i32x4 d[4][2], const int8_t* base,
                                           int off0, int off1) {
#pragma unroll
    for (int f = 0; f < 4; ++f) {
        d[f][0] = *reinterpret_cast<const i32x4*>(base + (FB + f) * (16 * BKB) + off0);
        d[f][1] = *reinterpret_cast<const i32x4*>(base + (FB + f) * (16 * BKB) + off1);
    }
}

template <int FB>
__device__ __forceinline__ void load_frag2(i32x4 d[2][2], const int8_t* base,
                                           int off0, int off1) {
#pragma unroll
    for (int f = 0; f < 2; ++f) {
        d[f][0] = *reinterpret_cast<const i32x4*>(base + (FB + f) * (16 * BKB) + off0);
        d[f][1] = *reinterpret_cast<const i32x4*>(base + (FB + f) * (16 * BKB) + off1);
    }
}

// one C-quadrant x K=128: 16 MFMAs, k-slice outer (no dependent back-to-back)
template <int AM, int AN>
__device__ __forceinline__ void mfma_quad(i32x4 acc[8][4], const i32x4 a[4][2],
                                          const i32x4 b[2][2]) {
#pragma unroll
    for (int ks = 0; ks < 2; ++ks)
#pragma unroll
        for (int mf = 0; mf < 4; ++mf)
#pragma unroll
            for (int nf = 0; nf < 2; ++nf)
                acc[AM + mf][AN + nf] = __builtin_amdgcn_mfma_i32_16x16x64_i8(
                    a[mf][ks], b[nf][ks], acc[AM + mf][AN + nf], 0, 0, 0);
}

#define WIN_END()                                               \
    __builtin_amdgcn_sched_barrier(0);                          \
    __builtin_amdgcn_s_barrier();                               \
    __builtin_amdgcn_sched_barrier(0);                          \
    __builtin_amdgcn_s_setprio(1)

#define MFMA_END()                                              \
    __builtin_amdgcn_s_setprio(0);                              \
    __builtin_amdgcn_s_barrier();                               \
    __builtin_amdgcn_sched_barrier(0)

#define MFMA_END_VM(N)                                          \
    __builtin_amdgcn_s_setprio(0);                              \
    asm volatile("s_waitcnt vmcnt(" #N ")" ::: "memory");       \
    __builtin_amdgcn_s_barrier();                               \
    __builtin_amdgcn_sched_barrier(0)

__global__ __launch_bounds__(512, 2) void bin_gemm_i8(
    const int8_t* __restrict__ A,    // [B_ROWS][IN_DIM] i8
    const int8_t* __restrict__ W,    // [OUT_DIM][IN_DIM] i8
    float* __restrict__ out,         // [B_ROWS][OUT_DIM] f32 (raw dot)
    float* __restrict__ colsum,
    float* __restrict__ colsumsq)
{
    __shared__ __align__(16) int8_t lds[2][2][BM * BKB];   // [buf][A=0/B=1] 128 KiB
    __shared__ float s_sum[BLKN];
    __shared__ float s_sq[BLKN];

    const int t      = threadIdx.x;
    const int lane   = t & 63;
    const int wave   = t >> 6;
    const int wm     = wave >> 2;          // 0..1
    const int wn     = wave & 3;           // 0..3
    const int lane16 = lane & 15;
    const int quad   = lane >> 4;

    // XCD-aware bijective block swizzle (512 workgroups, 512 % 8 == 0)
    const int flat = blockIdx.y * gridDim.x + blockIdx.x;
    const int swz  = (flat & 7) * (512 / 8) + (flat >> 3);
    const int row0 = (swz >> 4) * BM;      // batch-row block
    const int col0 = (swz & 15) * BLKN;    // out-col block

    if (t < BLKN) { s_sum[t] = 0.f; s_sq[t] = 0.f; }

    // ---- staging geometry: thread -> (row, 16B slot), swizzled global src ----
    const int r6 = t >> 3;                       // 0..63
    const int c8 = t & 7;                        // phys slot in 128-B row
    const int gslot = ((c8 ^ (r6 & 7)) << 4);    // swizzled global 16-B group
    const int rA0 = r6;                          // A rows: +{0,64} sel, +128 load1
    const int rB0 = r6 + (r6 & 32);              // B rows: +{0,32} sel, +128 load1

    const int8_t* pA = A + (size_t)(row0 + rA0) * IN_DIM + gslot;
    const int8_t* pW = W + (size_t)(col0 + rB0) * IN_DIM + gslot;
    int8_t* lA0 = &lds[0][0][rA0 * BKB + c8 * 16];
    int8_t* lB0 = &lds[0][1][rB0 * BKB + c8 * 16];

    // ---- read geometry: frag row = base+f*16+lane16; slot=(ks*4+quad)^row&7 ----
    const int sw   = lane & 7;
    const int off0 = ((quad ^ sw) << 4);
    const int off1 = (((4 + quad) ^ sw) << 4);
    const int8_t* rA = &lds[0][0][(wm * 128 + lane16) * BKB];
    const int8_t* rB = &lds[0][1][(wn * 64 + lane16) * BKB];

    i32x4 acc[8][4] = {};
    i32x4 alo[4][2], ahi[4][2], bb01[2][2], bb23[2][2];

    // ---- prologue: b0 full (tile0) + b1.{AQ0,BN0} (tile1); drain; barrier;
    //      THEN read ph1 operands (other waves' staging now visible) ----
    stage_pair(pA,                       lA0);               // b0.AQ0
    stage_pair(pA + (size_t)64 * IN_DIM, lA0 + 64 * BKB);    // b0.AQ1
    stage_pair(pW,                       lB0);               // b0.BN0
    stage_pair(pW + (size_t)32 * IN_DIM, lB0 + 32 * BKB);    // b0.BN1
    stage_pair(pA + BKB,                 lA0 + 65536);       // b1.AQ0
    stage_pair(pW + BKB,                 lB0 + 65536);       // b1.BN0
    asm volatile("s_waitcnt vmcnt(0)" ::: "memory");
    __builtin_amdgcn_s_barrier();
    __builtin_amdgcn_sched_barrier(0);
    load_frag4<0>(alo,  rA, off0, off1);                     // ph1 operands
    load_frag2<0>(bb01, rB, off0, off1);

#pragma unroll 1
    for (int it = 0; it < NIT; ++it) {
        const int tc1 = (2 * it + 1) & (NKT - 1);
        const int tn0 = (2 * it + 2) & (NKT - 1);   // wraps harmlessly at tail
        const int tn1 = (2 * it + 3) & (NKT - 1);

        // p1: reads bb23(b0); stage b1.AQ1(tc1); mfma alo*bb01 (b0)
        load_frag2<2>(bb23, rB, off0, off1);
        stage_pair(pA + (size_t)64 * IN_DIM + tc1 * BKB, lA0 + 65536 + 64 * BKB);
        WIN_END();
        mfma_quad<0, 0>(acc, alo, bb01);
        MFMA_END();

        // p2: reads ahi(b0); stage b1.BN1(tc1); mfma alo*bb23 (b0)
        load_frag4<4>(ahi, rA, off0, off1);
        stage_pair(pW + (size_t)32 * IN_DIM + tc1 * BKB, lB0 + 65536 + 32 * BKB);
        WIN_END();
        mfma_quad<0, 2>(acc, alo, bb23);
        MFMA_END();

        // p3: stage b0'.AQ0(tn0); mfma ahi*bb01 (b0)
        stage_pair(pA + tn0 * BKB, lA0);
        WIN_END();
        mfma_quad<4, 0>(acc, ahi, bb01);
        MFMA_END_VM(6);                          // drains prev-p7/p8: b1.AQ0,BN0

        // p4: reads alo+bb01(b1); stage b0'.BN0(tn0); mfma ahi*bb23 (b0)
        load_frag4<0>(alo,  rA + 65536, off0, off1);
        load_frag2<0>(bb01, rB + 65536, off0, off1);
        stage_pair(pW + tn0 * BKB, lB0);
        WIN_END();
        mfma_quad<4, 2>(acc, ahi, bb23);
        MFMA_END_VM(4);                          // drains p1/p2: b1.AQ1,BN1

        // p5: reads bb23(b1); stage b0'.AQ1(tn0); mfma alo*bb01 (b1)
        load_frag2<2>(bb23, rB + 65536, off0, off1);
        stage_pair(pA + (size_t)64 * IN_DIM + tn0 * BKB, lA0 + 64 * BKB);
        WIN_END();
        mfma_quad<0, 0>(acc, alo, bb01);
        MFMA_END();

        // p6: reads ahi(b1); stage b0'.BN1(tn0); mfma alo*bb23 (b1)
        load_frag4<4>(ahi, rA + 65536, off0, off1);
        stage_pair(pW + (size_t)32 * IN_DIM + tn0 * BKB, lB0 + 32 * BKB);
        WIN_END();
        mfma_quad<0, 2>(acc, alo, bb23);
        MFMA_END();

        // p7: stage b1'.AQ0(tn1); mfma ahi*bb01 (b1)
        stage_pair(pA + tn1 * BKB, lA0 + 65536);
        WIN_END();
        mfma_quad<4, 0>(acc, ahi, bb01);
        MFMA_END_VM(6);                          // drains p3/p4: b0'.AQ0,BN0

        // p8: reads alo+bb01(b0'); stage b1'.BN0(tn1); mfma ahi*bb23 (b1)
        load_frag4<0>(alo,  rA, off0, off1);
        load_frag2<0>(bb01, rB, off0, off1);
        stage_pair(pW + tn1 * BKB, lB0 + 65536);
        WIN_END();
        mfma_quad<4, 2>(acc, ahi, bb23);
        MFMA_END_VM(4);                          // drains p5/p6: b0'.AQ1,BN1
    }

    // ---- epilogue: write fp32 C, accumulate per-column BN partials ----
    float csum[4] = {0.f, 0.f, 0.f, 0.f};
    float csq[4]  = {0.f, 0.f, 0.f, 0.f};
#pragma unroll
    for (int mf = 0; mf < 8; ++mf) {
#pragma unroll
        for (int r = 0; r < 4; ++r) {
            int grow = row0 + wm * 128 + mf * 16 + quad * 4 + r;   // C/D row=quad*4+reg
            float* orow = out + (size_t)grow * OUT_DIM + col0 + wn * 64 + lane16;
#pragma unroll
            for (int nf = 0; nf < 4; ++nf) {
                float v = (float)acc[mf][nf][r];
                orow[nf * 16] = v;
                csum[nf] += v;
                csq[nf]  += v * v;
            }
        }
    }
#pragma unroll
    for (int nf = 0; nf < 4; ++nf) {
        csum[nf] += __shfl_xor(csum[nf], 16);
        csum[nf] += __shfl_xor(csum[nf], 32);
        csq[nf]  += __shfl_xor(csq[nf], 16);
        csq[nf]  += __shfl_xor(csq[nf], 32);
    }
    if (quad == 0) {
#pragma unroll
        for (int nf = 0; nf < 4; ++nf) {
            atomicAdd(&s_sum[wn * 64 + nf * 16 + lane16], csum[nf]);
            atomicAdd(&s_sq [wn * 64 + nf * 16 + lane16], csq[nf]);
        }
    }
    __syncthreads();
    if (t < BLKN) {
        atomicAdd(&colsum[col0 + t],   s_sum[t]);
        atomicAdd(&colsumsq[col0 + t], s_sq[t]);
    }
}

// ---------------------------------------------------------------------------
__global__ void bn_stats(const float* __restrict__ colsum,
                         const float* __restrict__ colsumsq,
                         float* __restrict__ mean, float* __restrict__ rstd) {
    int o = blockIdx.x * blockDim.x + threadIdx.x;
    float m = colsum[o] * (1.0f / B_ROWS);
    float v = colsumsq[o] * (1.0f / B_ROWS) - m * m;
    mean[o] = m;
    rstd[o] = rsqrtf(v + BN_EPS);
}

__global__ void bn_apply(float* __restrict__ out,
                         const float* __restrict__ mean,
                         const float* __restrict__ rstd) {
    size_t f = (size_t)blockIdx.x * blockDim.x + threadIdx.x;  // float4 index
    int c4 = (int)(f & (OUT_DIM / 4 - 1));
    float4 v = reinterpret_cast<float4*>(out)[f];
    float4 m = reinterpret_cast<const float4*>(mean)[c4];
    float4 r = reinterpret_cast<const float4*>(rstd)[c4];
    v.x = (v.x - m.x) * r.x;
    v.y = (v.y - m.y) * r.y;
    v.z = (v.z - m.z) * r.z;
    v.w = (v.w - m.w) * r.w;
    reinterpret_cast<float4*>(out)[f] = v;
}

// ---------------------------------------------------------------------------
extern "C" void kernel_launch(void* const* d_in, const int* in_sizes, int n_in,
                              void* d_out, int out_size, void* d_ws, size_t ws_size,
                              hipStream_t stream) {
    const float* x = (const float*)d_in[0];
    const float* w = (const float*)d_in[1];
    float* out = (float*)d_out;

    uint8_t* ws = (uint8_t*)d_ws;
    int8_t* xb = (int8_t*)ws;                                      // 33.55 MB
    int8_t* wb = (int8_t*)(ws + (size_t)B_ROWS * IN_DIM);          // 16.78 MB
    float* colsum   = (float*)(ws + (size_t)B_ROWS * IN_DIM
                                  + (size_t)OUT_DIM * IN_DIM);
    float* colsumsq = colsum + OUT_DIM;
    float* mean     = colsumsq + OUT_DIM;
    float* rstd     = mean + OUT_DIM;

    hipMemsetAsync(colsum, 0, 2 * OUT_DIM * sizeof(float), stream);

    pack_both<<<((B_ROWS + OUT_DIM) * (IN_DIM / 4)) / 256, 256, 0, stream>>>(
        x, w, (int*)xb, (int*)wb);

    bin_gemm_i8<<<dim3(OUT_DIM / BLKN, B_ROWS / BM), 512, 0, stream>>>(
        xb, wb, out, colsum, colsumsq);

    bn_stats<<<OUT_DIM / 256, 256, 0, stream>>>(colsum, colsumsq, mean, rstd);

    bn_apply<<<(unsigned)((size_t)B_ROWS * OUT_DIM / 4 / 256), 256, 0, stream>>>(
        out, mean, rstd);
}

// Round 4
// 428.483 us; speedup vs baseline: 1.1954x; 1.1954x over previous
//
#include <hip/hip_runtime.h>
#include <stdint.h>

#define B_ROWS 8192
#define IN_DIM 4096
#define OUT_DIM 4096
#define BN_EPS 1e-5f

#define BM 256                      // batch rows per block
#define BLKN 256                    // out cols per block
#define BKB 128                     // i8 K-bytes per K-tile
#define NKT (IN_DIM / BKB)          // 32 K-tiles
#define NIT (NKT / 2)               // 16 iterations (2 K-tiles each)

typedef __attribute__((ext_vector_type(4))) int i32x4;

// ---------------------------------------------------------------------------
// fp32 -> int8 sign pack: {-1, 0, +1}. Exact. x and w fused in one launch.
// ---------------------------------------------------------------------------
__device__ __forceinline__ int sign_byte(float f) {
    int s = (f > 0.f) ? 1 : ((f < 0.f) ? -1 : 0);
    return s & 0xFF;
}

#define XN (B_ROWS * IN_DIM / 4)    // float4 count of x

__global__ void pack_both(const float* __restrict__ x, const float* __restrict__ w,
                          int* __restrict__ xb, int* __restrict__ wb) {
    int gid = blockIdx.x * blockDim.x + threadIdx.x;
    const float* src = (gid < XN) ? x : w;
    int*         dst = (gid < XN) ? xb : wb;
    int          idx = (gid < XN) ? gid : gid - XN;
    float4 v = reinterpret_cast<const float4*>(src)[idx];
    dst[idx] = sign_byte(v.x) | (sign_byte(v.y) << 8) |
               (sign_byte(v.z) << 16) | (sign_byte(v.w) << 24);
}

// ---------------------------------------------------------------------------
// 256x256 8-phase i8 MFMA GEMM — the verified R1 schedule (152 us), restored
// verbatim. Reads in their OWN phase + lgkmcnt(0) drain after barrier (the
// m201 pattern). R3's pipelined-read variant regressed 57%: issuing ds_reads
// into registers still sourced by in-flight MFMAs forces compiler s_nop
// padding (no MFMA-completion counter exists). Do NOT re-introduce.
//
// Per-iteration (2 K-tiles; b0 = even, b1 = odd):
//   ph1: rd b0.A(mf0-3)+B(nf0-1) [12]  stage b1.BN1(tc1)   mfma Q(0-3,0-1)
//   ph2: rd b0.A(mf4-7)          [ 8]  stage b0'.AQ0(tn0)  mfma Q(4-7,0-1)
//   ph3: rd b0.B(nf2-3)          [ 4]  stage b0'.AQ1(tn0)  mfma Q(4-7,2-3)
//   ph4:                         [ 0]  stage b0'.BN0(tn0)  mfma Q(0-3,2-3)  vmcnt(6)
//   ph5-8: same on b1 (stages b0'.BN1, b1'.AQ0, b1'.AQ1, b1'.BN0)          vmcnt(6)
// vmcnt ladder (2 loads/stage, audited R3->R4): prologue 14 loads,
// vmcnt(6) completes all of b0. p4-end: 14 outstanding -> 6 completes all
// of b1 before ph5 reads it. p8-end: 14 -> 6 completes b0' before next ph1.
// Every read issues after the barrier following its covering vmcnt.
// ---------------------------------------------------------------------------
__device__ __forceinline__ void stage_pair(const int8_t* g0, int8_t* l0) {
    __builtin_amdgcn_global_load_lds(
        (const __attribute__((address_space(1))) void*)g0,
        (__attribute__((address_space(3))) void*)l0, 16, 0, 0);
    __builtin_amdgcn_global_load_lds(
        (const __attribute__((address_space(1))) void*)(g0 + (size_t)128 * IN_DIM),
        (__attribute__((address_space(3))) void*)(l0 + 128 * BKB), 16, 0, 0);
}

template <int FB>
__device__ __forceinline__ void load_frag4(i32x4 d[4][2], const int8_t* base,
                                           int off0, int off1) {
#pragma unroll
    for (int f = 0; f < 4; ++f) {
        d[f][0] = *reinterpret_cast<const i32x4*>(base + (FB + f) * (16 * BKB) + off0);
        d[f][1] = *reinterpret_cast<const i32x4*>(base + (FB + f) * (16 * BKB) + off1);
    }
}

template <int FB>
__device__ __forceinline__ void load_frag2(i32x4 d[2][2], const int8_t* base,
                                           int off0, int off1) {
#pragma unroll
    for (int f = 0; f < 2; ++f) {
        d[f][0] = *reinterpret_cast<const i32x4*>(base + (FB + f) * (16 * BKB) + off0);
        d[f][1] = *reinterpret_cast<const i32x4*>(base + (FB + f) * (16 * BKB) + off1);
    }
}

// one C-quadrant x K=128: 16 MFMAs (accumulator chains are full-rate, m119)
template <int AM, int AN>
__device__ __forceinline__ void mfma_quad(i32x4 acc[8][4], const i32x4 a[4][2],
                                          const i32x4 b[2][2]) {
#pragma unroll
    for (int mf = 0; mf < 4; ++mf)
#pragma unroll
        for (int nf = 0; nf < 2; ++nf) {
            acc[AM + mf][AN + nf] = __builtin_amdgcn_mfma_i32_16x16x64_i8(
                a[mf][0], b[nf][0], acc[AM + mf][AN + nf], 0, 0, 0);
            acc[AM + mf][AN + nf] = __builtin_amdgcn_mfma_i32_16x16x64_i8(
                a[mf][1], b[nf][1], acc[AM + mf][AN + nf], 0, 0, 0);
        }
}

#define PHASE_MID()                                             \
    __builtin_amdgcn_s_barrier();                               \
    asm volatile("s_waitcnt lgkmcnt(0)" ::: "memory");          \
    __builtin_amdgcn_sched_barrier(0);                          \
    __builtin_amdgcn_s_setprio(1)

#define PHASE_END()                                             \
    __builtin_amdgcn_s_setprio(0);                              \
    __builtin_amdgcn_s_barrier()

#define PHASE_END_VM()                                          \
    __builtin_amdgcn_s_setprio(0);                              \
    asm volatile("s_waitcnt vmcnt(6)" ::: "memory");            \
    __builtin_amdgcn_s_barrier()

__global__ __launch_bounds__(512, 2) void bin_gemm_i8(
    const int8_t* __restrict__ A,    // [B_ROWS][IN_DIM] i8
    const int8_t* __restrict__ W,    // [OUT_DIM][IN_DIM] i8
    float* __restrict__ out,         // [B_ROWS][OUT_DIM] f32 (raw dot)
    float* __restrict__ colsum,
    float* __restrict__ colsumsq)
{
    __shared__ __align__(16) int8_t lds[2][2][BM * BKB];   // [buf][A=0/B=1] 128 KiB
    __shared__ float s_sum[BLKN];
    __shared__ float s_sq[BLKN];

    const int t      = threadIdx.x;
    const int lane   = t & 63;
    const int wave   = t >> 6;
    const int wm     = wave >> 2;          // 0..1
    const int wn     = wave & 3;           // 0..3
    const int lane16 = lane & 15;
    const int quad   = lane >> 4;

    // XCD-aware bijective block swizzle (512 workgroups, 512 % 8 == 0)
    const int flat = blockIdx.y * gridDim.x + blockIdx.x;
    const int swz  = (flat & 7) * (512 / 8) + (flat >> 3);
    const int row0 = (swz >> 4) * BM;      // batch-row block
    const int col0 = (swz & 15) * BLKN;    // out-col block

    if (t < BLKN) { s_sum[t] = 0.f; s_sq[t] = 0.f; }

    // ---- staging geometry: thread -> (row, 16B slot), swizzled global src ----
    const int r6 = t >> 3;                       // 0..63
    const int c8 = t & 7;                        // phys slot in 128-B row
    const int gslot = ((c8 ^ (r6 & 7)) << 4);    // swizzled global 16-B group
    const int rA0 = r6;                          // A rows: +{0,64} sel, +128 load1
    const int rB0 = r6 + (r6 & 32);              // B rows: +{0,32} sel, +128 load1

    const int8_t* pA = A + (size_t)(row0 + rA0) * IN_DIM + gslot;
    const int8_t* pW = W + (size_t)(col0 + rB0) * IN_DIM + gslot;
    int8_t* lA0 = &lds[0][0][rA0 * BKB + c8 * 16];
    int8_t* lB0 = &lds[0][1][rB0 * BKB + c8 * 16];

    // ---- read geometry: frag row = base+f*16+lane16; slot=(ks*4+quad)^row&7 ----
    const int sw   = lane & 7;
    const int off0 = ((quad ^ sw) << 4);
    const int off1 = (((4 + quad) ^ sw) << 4);
    const int8_t* rA = &lds[0][0][(wm * 128 + lane16) * BKB];
    const int8_t* rB = &lds[0][1][(wn * 64 + lane16) * BKB];

    i32x4 acc[8][4] = {};
    i32x4 alo[4][2], ahi[4][2], bb[2][2];

    // ---- prologue: tile0 -> buf0 full; tile1 -> buf1 AQ0,AQ1,BN0 (14 loads) ----
    stage_pair(pA,                             lA0);                        // b0.AQ0
    stage_pair(pA + (size_t)64 * IN_DIM,       lA0 + 64 * BKB);             // b0.AQ1
    stage_pair(pW,                             lB0);                        // b0.BN0
    stage_pair(pW + (size_t)32 * IN_DIM,       lB0 + 32 * BKB);             // b0.BN1
    stage_pair(pA + BKB,                       lA0 + 65536);                // b1.AQ0
    stage_pair(pA + (size_t)64 * IN_DIM + BKB, lA0 + 65536 + 64 * BKB);     // b1.AQ1
    stage_pair(pW + BKB,                       lB0 + 65536);                // b1.BN0
    asm volatile("s_waitcnt vmcnt(6)" ::: "memory");                        // b0 done
    __builtin_amdgcn_s_barrier();

#pragma unroll 1
    for (int it = 0; it < NIT; ++it) {
        const int tc1 = (2 * it + 1) & (NKT - 1);
        const int tn0 = (2 * it + 2) & (NKT - 1);   // wraps harmlessly on last iter
        const int tn1 = (2 * it + 3) & (NKT - 1);

        // ================= K-tile in buf0 =================
        // phase 1
        load_frag4<0>(alo, rA, off0, off1);
        load_frag2<0>(bb, rB, off0, off1);
        stage_pair(pW + (size_t)32 * IN_DIM + tc1 * BKB, lB0 + 65536 + 32 * BKB);
        PHASE_MID();
        mfma_quad<0, 0>(acc, alo, bb);
        PHASE_END();

        // phase 2
        load_frag4<4>(ahi, rA, off0, off1);
        stage_pair(pA + tn0 * BKB, lA0);
        PHASE_MID();
        mfma_quad<4, 0>(acc, ahi, bb);
        PHASE_END();

        // phase 3
        load_frag2<2>(bb, rB, off0, off1);
        stage_pair(pA + (size_t)64 * IN_DIM + tn0 * BKB, lA0 + 64 * BKB);
        PHASE_MID();
        mfma_quad<4, 2>(acc, ahi, bb);
        PHASE_END();

        // phase 4
        stage_pair(pW + tn0 * BKB, lB0);
        PHASE_MID();
        mfma_quad<0, 2>(acc, alo, bb);
        PHASE_END_VM();

        // ================= K-tile in buf1 =================
        // phase 5
        load_frag4<0>(alo, rA + 65536, off0, off1);
        load_frag2<0>(bb, rB + 65536, off0, off1);
        stage_pair(pW + (size_t)32 * IN_DIM + tn0 * BKB, lB0 + 32 * BKB);
        PHASE_MID();
        mfma_quad<0, 0>(acc, alo, bb);
        PHASE_END();

        // phase 6
        load_frag4<4>(ahi, rA + 65536, off0, off1);
        stage_pair(pA + tn1 * BKB, lA0 + 65536);
        PHASE_MID();
        mfma_quad<4, 0>(acc, ahi, bb);
        PHASE_END();

        // phase 7
        load_frag2<2>(bb, rB + 65536, off0, off1);
        stage_pair(pA + (size_t)64 * IN_DIM + tn1 * BKB, lA0 + 65536 + 64 * BKB);
        PHASE_MID();
        mfma_quad<4, 2>(acc, ahi, bb);
        PHASE_END();

        // phase 8
        stage_pair(pW + tn1 * BKB, lB0 + 65536);
        PHASE_MID();
        mfma_quad<0, 2>(acc, alo, bb);
        PHASE_END_VM();
    }

    // ---- epilogue: write fp32 C, accumulate per-column BN partials ----
    float csum[4] = {0.f, 0.f, 0.f, 0.f};
    float csq[4]  = {0.f, 0.f, 0.f, 0.f};
#pragma unroll
    for (int mf = 0; mf < 8; ++mf) {
#pragma unroll
        for (int r = 0; r < 4; ++r) {
            int grow = row0 + wm * 128 + mf * 16 + quad * 4 + r;   // C/D row=quad*4+reg
            float* orow = out + (size_t)grow * OUT_DIM + col0 + wn * 64 + lane16;
#pragma unroll
            for (int nf = 0; nf < 4; ++nf) {
                float v = (float)acc[mf][nf][r];
                orow[nf * 16] = v;
                csum[nf] += v;
                csq[nf]  += v * v;
            }
        }
    }
#pragma unroll
    for (int nf = 0; nf < 4; ++nf) {
        csum[nf] += __shfl_xor(csum[nf], 16);
        csum[nf] += __shfl_xor(csum[nf], 32);
        csq[nf]  += __shfl_xor(csq[nf], 16);
        csq[nf]  += __shfl_xor(csq[nf], 32);
    }
    if (quad == 0) {
#pragma unroll
        for (int nf = 0; nf < 4; ++nf) {
            atomicAdd(&s_sum[wn * 64 + nf * 16 + lane16], csum[nf]);
            atomicAdd(&s_sq [wn * 64 + nf * 16 + lane16], csq[nf]);
        }
    }
    __syncthreads();
    if (t < BLKN) {
        atomicAdd(&colsum[col0 + t],   s_sum[t]);
        atomicAdd(&colsumsq[col0 + t], s_sq[t]);
    }
}

// ---------------------------------------------------------------------------
// BN normalize, stats fused: each thread recomputes mean/rstd for its 4
// columns from colsum/colsumsq (32 B L2-hot reads + 4 rsqrt per 16 B store —
// free in a memory-bound kernel; saves the bn_stats launch).
// ---------------------------------------------------------------------------
__global__ void bn_apply(float* __restrict__ out,
                         const float* __restrict__ colsum,
                         const float* __restrict__ colsumsq) {
    size_t f = (size_t)blockIdx.x * blockDim.x + threadIdx.x;  // float4 index
    int c4 = (int)(f & (OUT_DIM / 4 - 1));
    float4 v  = reinterpret_cast<float4*>(out)[f];
    float4 cs = reinterpret_cast<const float4*>(colsum)[c4];
    float4 cq = reinterpret_cast<const float4*>(colsumsq)[c4];
    const float inv = 1.0f / B_ROWS;
    float mx = cs.x * inv, my = cs.y * inv, mz = cs.z * inv, mw = cs.w * inv;
    float rx = rsqrtf(cq.x * inv - mx * mx + BN_EPS);
    float ry = rsqrtf(cq.y * inv - my * my + BN_EPS);
    float rz = rsqrtf(cq.z * inv - mz * mz + BN_EPS);
    float rw = rsqrtf(cq.w * inv - mw * mw + BN_EPS);
    v.x = (v.x - mx) * rx;
    v.y = (v.y - my) * ry;
    v.z = (v.z - mz) * rz;
    v.w = (v.w - mw) * rw;
    reinterpret_cast<float4*>(out)[f] = v;
}

// ---------------------------------------------------------------------------
extern "C" void kernel_launch(void* const* d_in, const int* in_sizes, int n_in,
                              void* d_out, int out_size, void* d_ws, size_t ws_size,
                              hipStream_t stream) {
    const float* x = (const float*)d_in[0];
    const float* w = (const float*)d_in[1];
    float* out = (float*)d_out;

    uint8_t* ws = (uint8_t*)d_ws;
    int8_t* xb = (int8_t*)ws;                                      // 33.55 MB
    int8_t* wb = (int8_t*)(ws + (size_t)B_ROWS * IN_DIM);          // 16.78 MB
    float* colsum   = (float*)(ws + (size_t)B_ROWS * IN_DIM
                                  + (size_t)OUT_DIM * IN_DIM);
    float* colsumsq = colsum + OUT_DIM;

    hipMemsetAsync(colsum, 0, 2 * OUT_DIM * sizeof(float), stream);

    pack_both<<<((B_ROWS + OUT_DIM) * (IN_DIM / 4)) / 256, 256, 0, stream>>>(
        x, w, (int*)xb, (int*)wb);

    bin_gemm_i8<<<dim3(OUT_DIM / BLKN, B_ROWS / BM), 512, 0, stream>>>(
        xb, wb, out, colsum, colsumsq);

    bn_apply<<<(unsigned)((size_t)B_ROWS * OUT_DIM / 4 / 256), 256, 0, stream>>>(
        out, colsum, colsumsq);
}

// Round 5
// 412.102 us; speedup vs baseline: 1.2429x; 1.0397x over previous
//
#include <hip/hip_runtime.h>
#include <stdint.h>

#define B_ROWS 8192
#define IN_DIM 4096
#define OUT_DIM 4096
#define BN_EPS 1e-5f

#define BM 256                      // batch rows per block
#define BLKN 256                    // out cols per block
#define BKB 128                     // i8 K-bytes per K-tile
#define NKT (IN_DIM / BKB)          // 32 K-tiles
#define NIT (NKT / 2)               // 16 iterations (2 K-tiles each)

typedef __attribute__((ext_vector_type(4))) int   i32x4;
typedef __attribute__((ext_vector_type(4))) short s16x4;

// ---------------------------------------------------------------------------
// fp32 -> int8 sign pack: {-1, 0, +1}. Exact. x and w fused in one launch.
// ---------------------------------------------------------------------------
__device__ __forceinline__ int sign_byte(float f) {
    int s = (f > 0.f) ? 1 : ((f < 0.f) ? -1 : 0);
    return s & 0xFF;
}

#define XN (B_ROWS * IN_DIM / 4)    // float4 count of x (block-aligned: XN%256==0)

__global__ void pack_both(const float* __restrict__ x, const float* __restrict__ w,
                          int* __restrict__ xb, int* __restrict__ wb) {
    int gid = blockIdx.x * blockDim.x + threadIdx.x;
    const float* src = (gid < XN) ? x : w;
    int*         dst = (gid < XN) ? xb : wb;
    int          idx = (gid < XN) ? gid : gid - XN;
    float4 v = reinterpret_cast<const float4*>(src)[idx];
    dst[idx] = sign_byte(v.x) | (sign_byte(v.y) << 8) |
               (sign_byte(v.z) << 16) | (sign_byte(v.w) << 24);
}

// ---------------------------------------------------------------------------
// 256x256 8-phase i8 MFMA GEMM — the verified R1 schedule (152 us). Reads in
// their OWN phase + lgkmcnt(0) drain after barrier (the m201 pattern). R3's
// pipelined-read variant regressed 57%: ds_reads into registers still
// sourced by in-flight MFMAs force compiler s_nop hazard padding. Do NOT
// re-introduce without a ping-pong fragment register set (no budget: 128
// VGPR + 128 acc = 256 unified = the 2-wave/SIMD occupancy limit).
//
// R5 delta: epilogue store type templated (RawT = short when workspace has
// room): |dot| <= 4096 fits i16 exactly -> halves GEMM write + bn read
// traffic. K-loop untouched.
//
// Per-iteration (2 K-tiles; b0 = even, b1 = odd):
//   ph1: rd b0.A(mf0-3)+B(nf0-1) [12]  stage b1.BN1(tc1)   mfma Q(0-3,0-1)
//   ph2: rd b0.A(mf4-7)          [ 8]  stage b0'.AQ0(tn0)  mfma Q(4-7,0-1)
//   ph3: rd b0.B(nf2-3)          [ 4]  stage b0'.AQ1(tn0)  mfma Q(4-7,2-3)
//   ph4:                         [ 0]  stage b0'.BN0(tn0)  mfma Q(0-3,2-3)  vmcnt(6)
//   ph5-8: same on b1 (stages b0'.BN1, b1'.AQ0, b1'.AQ1, b1'.BN0)          vmcnt(6)
// vmcnt ladder (2 loads/stage): prologue 14 loads, vmcnt(6) completes b0.
// p4-end: 14 outstanding -> 6 completes all of b1 before ph5 reads it.
// p8-end: completes b0' before next ph1. Every read issues after the
// barrier following its covering vmcnt (cross-wave safe).
// ---------------------------------------------------------------------------
__device__ __forceinline__ void stage_pair(const int8_t* g0, int8_t* l0) {
    __builtin_amdgcn_global_load_lds(
        (const __attribute__((address_space(1))) void*)g0,
        (__attribute__((address_space(3))) void*)l0, 16, 0, 0);
    __builtin_amdgcn_global_load_lds(
        (const __attribute__((address_space(1))) void*)(g0 + (size_t)128 * IN_DIM),
        (__attribute__((address_space(3))) void*)(l0 + 128 * BKB), 16, 0, 0);
}

template <int FB>
__device__ __forceinline__ void load_frag4(i32x4 d[4][2], const int8_t* base,
                                           int off0, int off1) {
#pragma unroll
    for (int f = 0; f < 4; ++f) {
        d[f][0] = *reinterpret_cast<const i32x4*>(base + (FB + f) * (16 * BKB) + off0);
        d[f][1] = *reinterpret_cast<const i32x4*>(base + (FB + f) * (16 * BKB) + off1);
    }
}

template <int FB>
__device__ __forceinline__ void load_frag2(i32x4 d[2][2], const int8_t* base,
                                           int off0, int off1) {
#pragma unroll
    for (int f = 0; f < 2; ++f) {
        d[f][0] = *reinterpret_cast<const i32x4*>(base + (FB + f) * (16 * BKB) + off0);
        d[f][1] = *reinterpret_cast<const i32x4*>(base + (FB + f) * (16 * BKB) + off1);
    }
}

// one C-quadrant x K=128: 16 MFMAs
template <int AM, int AN>
__device__ __forceinline__ void mfma_quad(i32x4 acc[8][4], const i32x4 a[4][2],
                                          const i32x4 b[2][2]) {
#pragma unroll
    for (int mf = 0; mf < 4; ++mf)
#pragma unroll
        for (int nf = 0; nf < 2; ++nf) {
            acc[AM + mf][AN + nf] = __builtin_amdgcn_mfma_i32_16x16x64_i8(
                a[mf][0], b[nf][0], acc[AM + mf][AN + nf], 0, 0, 0);
            acc[AM + mf][AN + nf] = __builtin_amdgcn_mfma_i32_16x16x64_i8(
                a[mf][1], b[nf][1], acc[AM + mf][AN + nf], 0, 0, 0);
        }
}

#define PHASE_MID()                                             \
    __builtin_amdgcn_s_barrier();                               \
    asm volatile("s_waitcnt lgkmcnt(0)" ::: "memory");          \
    __builtin_amdgcn_sched_barrier(0);                          \
    __builtin_amdgcn_s_setprio(1)

#define PHASE_END()                                             \
    __builtin_amdgcn_s_setprio(0);                              \
    __builtin_amdgcn_s_barrier()

#define PHASE_END_VM()                                          \
    __builtin_amdgcn_s_setprio(0);                              \
    asm volatile("s_waitcnt vmcnt(6)" ::: "memory");            \
    __builtin_amdgcn_s_barrier()

template <typename RawT>
__global__ __launch_bounds__(512, 2) void bin_gemm_i8(
    const int8_t* __restrict__ A,    // [B_ROWS][IN_DIM] i8
    const int8_t* __restrict__ W,    // [OUT_DIM][IN_DIM] i8
    RawT* __restrict__ raw,          // [B_ROWS][OUT_DIM] raw dot (i16 or f32)
    float* __restrict__ colsum,
    float* __restrict__ colsumsq)
{
    __shared__ __align__(16) int8_t lds[2][2][BM * BKB];   // [buf][A=0/B=1] 128 KiB
    __shared__ float s_sum[BLKN];
    __shared__ float s_sq[BLKN];

    const int t      = threadIdx.x;
    const int lane   = t & 63;
    const int wave   = t >> 6;
    const int wm     = wave >> 2;          // 0..1
    const int wn     = wave & 3;           // 0..3
    const int lane16 = lane & 15;
    const int quad   = lane >> 4;

    // XCD-aware bijective block swizzle (512 workgroups, 512 % 8 == 0)
    const int flat = blockIdx.y * gridDim.x + blockIdx.x;
    const int swz  = (flat & 7) * (512 / 8) + (flat >> 3);
    const int row0 = (swz >> 4) * BM;      // batch-row block
    const int col0 = (swz & 15) * BLKN;    // out-col block

    if (t < BLKN) { s_sum[t] = 0.f; s_sq[t] = 0.f; }

    // ---- staging geometry: thread -> (row, 16B slot), swizzled global src ----
    const int r6 = t >> 3;                       // 0..63
    const int c8 = t & 7;                        // phys slot in 128-B row
    const int gslot = ((c8 ^ (r6 & 7)) << 4);    // swizzled global 16-B group
    const int rA0 = r6;                          // A rows: +{0,64} sel, +128 load1
    const int rB0 = r6 + (r6 & 32);              // B rows: +{0,32} sel, +128 load1

    const int8_t* pA = A + (size_t)(row0 + rA0) * IN_DIM + gslot;
    const int8_t* pW = W + (size_t)(col0 + rB0) * IN_DIM + gslot;
    int8_t* lA0 = &lds[0][0][rA0 * BKB + c8 * 16];
    int8_t* lB0 = &lds[0][1][rB0 * BKB + c8 * 16];

    // ---- read geometry: frag row = base+f*16+lane16; slot=(ks*4+quad)^row&7 ----
    const int sw   = lane & 7;
    const int off0 = ((quad ^ sw) << 4);
    const int off1 = (((4 + quad) ^ sw) << 4);
    const int8_t* rA = &lds[0][0][(wm * 128 + lane16) * BKB];
    const int8_t* rB = &lds[0][1][(wn * 64 + lane16) * BKB];

    i32x4 acc[8][4] = {};
    i32x4 alo[4][2], ahi[4][2], bb[2][2];

    // ---- prologue: tile0 -> buf0 full; tile1 -> buf1 AQ0,AQ1,BN0 (14 loads) ----
    stage_pair(pA,                             lA0);                        // b0.AQ0
    stage_pair(pA + (size_t)64 * IN_DIM,       lA0 + 64 * BKB);             // b0.AQ1
    stage_pair(pW,                             lB0);                        // b0.BN0
    stage_pair(pW + (size_t)32 * IN_DIM,       lB0 + 32 * BKB);             // b0.BN1
    stage_pair(pA + BKB,                       lA0 + 65536);                // b1.AQ0
    stage_pair(pA + (size_t)64 * IN_DIM + BKB, lA0 + 65536 + 64 * BKB);     // b1.AQ1
    stage_pair(pW + BKB,                       lB0 + 65536);                // b1.BN0
    asm volatile("s_waitcnt vmcnt(6)" ::: "memory");                        // b0 done
    __builtin_amdgcn_s_barrier();

#pragma unroll 1
    for (int it = 0; it < NIT; ++it) {
        const int tc1 = (2 * it + 1) & (NKT - 1);
        const int tn0 = (2 * it + 2) & (NKT - 1);   // wraps harmlessly on last iter
        const int tn1 = (2 * it + 3) & (NKT - 1);

        // ================= K-tile in buf0 =================
        // phase 1
        load_frag4<0>(alo, rA, off0, off1);
        load_frag2<0>(bb, rB, off0, off1);
        stage_pair(pW + (size_t)32 * IN_DIM + tc1 * BKB, lB0 + 65536 + 32 * BKB);
        PHASE_MID();
        mfma_quad<0, 0>(acc, alo, bb);
        PHASE_END();

        // phase 2
        load_frag4<4>(ahi, rA, off0, off1);
        stage_pair(pA + tn0 * BKB, lA0);
        PHASE_MID();
        mfma_quad<4, 0>(acc, ahi, bb);
        PHASE_END();

        // phase 3
        load_frag2<2>(bb, rB, off0, off1);
        stage_pair(pA + (size_t)64 * IN_DIM + tn0 * BKB, lA0 + 64 * BKB);
        PHASE_MID();
        mfma_quad<4, 2>(acc, ahi, bb);
        PHASE_END();

        // phase 4
        stage_pair(pW + tn0 * BKB, lB0);
        PHASE_MID();
        mfma_quad<0, 2>(acc, alo, bb);
        PHASE_END_VM();

        // ================= K-tile in buf1 =================
        // phase 5
        load_frag4<0>(alo, rA + 65536, off0, off1);
        load_frag2<0>(bb, rB + 65536, off0, off1);
        stage_pair(pW + (size_t)32 * IN_DIM + tn0 * BKB, lB0 + 32 * BKB);
        PHASE_MID();
        mfma_quad<0, 0>(acc, alo, bb);
        PHASE_END();

        // phase 6
        load_frag4<4>(ahi, rA + 65536, off0, off1);
        stage_pair(pA + tn1 * BKB, lA0 + 65536);
        PHASE_MID();
        mfma_quad<4, 0>(acc, ahi, bb);
        PHASE_END();

        // phase 7
        load_frag2<2>(bb, rB + 65536, off0, off1);
        stage_pair(pA + (size_t)64 * IN_DIM + tn1 * BKB, lA0 + 65536 + 64 * BKB);
        PHASE_MID();
        mfma_quad<4, 2>(acc, ahi, bb);
        PHASE_END();

        // phase 8
        stage_pair(pW + tn1 * BKB, lB0 + 65536);
        PHASE_MID();
        mfma_quad<0, 2>(acc, alo, bb);
        PHASE_END_VM();
    }

    // ---- epilogue: write raw C (RawT), accumulate per-column BN partials ----
    float csum[4] = {0.f, 0.f, 0.f, 0.f};
    float csq[4]  = {0.f, 0.f, 0.f, 0.f};
#pragma unroll
    for (int mf = 0; mf < 8; ++mf) {
#pragma unroll
        for (int r = 0; r < 4; ++r) {
            int grow = row0 + wm * 128 + mf * 16 + quad * 4 + r;   // C/D row=quad*4+reg
            RawT* orow = raw + (size_t)grow * OUT_DIM + col0 + wn * 64 + lane16;
#pragma unroll
            for (int nf = 0; nf < 4; ++nf) {
                int iv = acc[mf][nf][r];
                orow[nf * 16] = (RawT)iv;       // exact: |dot| <= 4096
                float v = (float)iv;
                csum[nf] += v;
                csq[nf]  += v * v;
            }
        }
    }
#pragma unroll
    for (int nf = 0; nf < 4; ++nf) {
        csum[nf] += __shfl_xor(csum[nf], 16);
        csum[nf] += __shfl_xor(csum[nf], 32);
        csq[nf]  += __shfl_xor(csq[nf], 16);
        csq[nf]  += __shfl_xor(csq[nf], 32);
    }
    if (quad == 0) {
#pragma unroll
        for (int nf = 0; nf < 4; ++nf) {
            atomicAdd(&s_sum[wn * 64 + nf * 16 + lane16], csum[nf]);
            atomicAdd(&s_sq [wn * 64 + nf * 16 + lane16], csq[nf]);
        }
    }
    __syncthreads();
    if (t < BLKN) {
        atomicAdd(&colsum[col0 + t],   s_sum[t]);
        atomicAdd(&colsumsq[col0 + t], s_sq[t]);
    }
}

// ---------------------------------------------------------------------------
// BN normalize (stats fused: mean/rstd recomputed per thread from L2-hot
// colsum/colsumsq). i16-raw variant reads 8 B/thread, writes 16 B/thread.
// ---------------------------------------------------------------------------
__global__ void bn_apply_i16(float* __restrict__ out,
                             const short* __restrict__ raw,
                             const float* __restrict__ colsum,
                             const float* __restrict__ colsumsq) {
    size_t f = (size_t)blockIdx.x * blockDim.x + threadIdx.x;  // 4-col group index
    int c4 = (int)(f & (OUT_DIM / 4 - 1));
    s16x4  rv = reinterpret_cast<const s16x4*>(raw)[f];
    float4 cs = reinterpret_cast<const float4*>(colsum)[c4];
    float4 cq = reinterpret_cast<const float4*>(colsumsq)[c4];
    const float inv = 1.0f / B_ROWS;
    float mx = cs.x * inv, my = cs.y * inv, mz = cs.z * inv, mw = cs.w * inv;
    float4 v;
    v.x = ((float)rv[0] - mx) * rsqrtf(cq.x * inv - mx * mx + BN_EPS);
    v.y = ((float)rv[1] - my) * rsqrtf(cq.y * inv - my * my + BN_EPS);
    v.z = ((float)rv[2] - mz) * rsqrtf(cq.z * inv - mz * mz + BN_EPS);
    v.w = ((float)rv[3] - mw) * rsqrtf(cq.w * inv - mw * mw + BN_EPS);
    reinterpret_cast<float4*>(out)[f] = v;
}

__global__ void bn_apply_f32(float* __restrict__ out,
                             const float* __restrict__ colsum,
                             const float* __restrict__ colsumsq) {
    size_t f = (size_t)blockIdx.x * blockDim.x + threadIdx.x;  // float4 index
    int c4 = (int)(f & (OUT_DIM / 4 - 1));
    float4 v  = reinterpret_cast<float4*>(out)[f];
    float4 cs = reinterpret_cast<const float4*>(colsum)[c4];
    float4 cq = reinterpret_cast<const float4*>(colsumsq)[c4];
    const float inv = 1.0f / B_ROWS;
    float mx = cs.x * inv, my = cs.y * inv, mz = cs.z * inv, mw = cs.w * inv;
    v.x = (v.x - mx) * rsqrtf(cq.x * inv - mx * mx + BN_EPS);
    v.y = (v.y - my) * rsqrtf(cq.y * inv - my * my + BN_EPS);
    v.z = (v.z - mz) * rsqrtf(cq.z * inv - mz * mz + BN_EPS);
    v.w = (v.w - mw) * rsqrtf(cq.w * inv - mw * mw + BN_EPS);
    reinterpret_cast<float4*>(out)[f] = v;
}

// ---------------------------------------------------------------------------
extern "C" void kernel_launch(void* const* d_in, const int* in_sizes, int n_in,
                              void* d_out, int out_size, void* d_ws, size_t ws_size,
                              hipStream_t stream) {
    const float* x = (const float*)d_in[0];
    const float* w = (const float*)d_in[1];
    float* out = (float*)d_out;

    const size_t xb_sz  = (size_t)B_ROWS * IN_DIM;       // 33.55 MB
    const size_t wb_sz  = (size_t)OUT_DIM * IN_DIM;      // 16.78 MB
    const size_t raw_sz = (size_t)B_ROWS * OUT_DIM * 2;  // 67.11 MB (i16)
    const size_t col_sz = 2 * OUT_DIM * sizeof(float);

    uint8_t* ws = (uint8_t*)d_ws;
    int8_t* xb = (int8_t*)ws;
    int8_t* wb = (int8_t*)(ws + xb_sz);

    const bool use_i16 = ws_size >= xb_sz + wb_sz + raw_sz + col_sz;

    if (use_i16) {
        short* raw      = (short*)(ws + xb_sz + wb_sz);
        float* colsum   = (float*)(ws + xb_sz + wb_sz + raw_sz);
        float* colsumsq = colsum + OUT_DIM;

        hipMemsetAsync(colsum, 0, col_sz, stream);
        pack_both<<<((B_ROWS + OUT_DIM) * (IN_DIM / 4)) / 256, 256, 0, stream>>>(
            x, w, (int*)xb, (int*)wb);
        bin_gemm_i8<short><<<dim3(OUT_DIM / BLKN, B_ROWS / BM), 512, 0, stream>>>(
            xb, wb, raw, colsum, colsumsq);
        bn_apply_i16<<<(unsigned)((size_t)B_ROWS * OUT_DIM / 4 / 256), 256, 0,
                       stream>>>(out, raw, colsum, colsumsq);
    } else {
        // fallback: raw f32 in the output buffer (R4 path, verified 428 us)
        float* colsum   = (float*)(ws + xb_sz + wb_sz);
        float* colsumsq = colsum + OUT_DIM;

        hipMemsetAsync(colsum, 0, col_sz, stream);
        pack_both<<<((B_ROWS + OUT_DIM) * (IN_DIM / 4)) / 256, 256, 0, stream>>>(
            x, w, (int*)xb, (int*)wb);
        bin_gemm_i8<float><<<dim3(OUT_DIM / BLKN, B_ROWS / BM), 512, 0, stream>>>(
            xb, wb, out, colsum, colsumsq);
        bn_apply_f32<<<(unsigned)((size_t)B_ROWS * OUT_DIM / 4 / 256), 256, 0,
                       stream>>>(out, colsum, colsumsq);
    }
}